// Round 9
// baseline (48.203 us; speedup 1.0000x reference)
//
#include <hip/hip_runtime.h>
#include <stdint.h>

#define IN_F 512
#define OUT_F 768
#define BD 256
#define ID 16
#define ND 256
#define CD 4096   // B*I columns
#define MS 20     // Msh row stride (16+4 pad)

typedef __bf16 bf16x8 __attribute__((ext_vector_type(8)));
typedef float f32x4 __attribute__((ext_vector_type(4)));

__device__ __forceinline__ unsigned short f2bf(float f) {
    union { float f; uint32_t u; } v; v.f = f;
    uint32_t u = v.u + 0x7FFFu + ((v.u >> 16) & 1u);  // RNE
    return (unsigned short)(u >> 16);
}

// ---- prep: T -> Tt bf16 fragment layout [f>>3][c][f&7]; x -> xbf bf16 ----
__global__ __launch_bounds__(256) void prep_kernel(const float* __restrict__ x,
                                                   const float* __restrict__ T,
                                                   unsigned short* __restrict__ Tt,
                                                   unsigned short* __restrict__ xbf) {
    const int bid = blockIdx.x;
    const int t = threadIdx.x;
    if (bid < 2048) {
        int gidx = bid * 256 + t;
        int f = gidx >> 10;              // 0..511
        int c = (gidx & 1023) * 4;       // 0..4092
        float4 v = *reinterpret_cast<const float4*>(T + (size_t)f * CD + c);
        unsigned short* base = Tt + (size_t)(f >> 3) * (CD * 8) + (f & 7);
        base[(size_t)(c + 0) * 8] = f2bf(v.x);
        base[(size_t)(c + 1) * 8] = f2bf(v.y);
        base[(size_t)(c + 2) * 8] = f2bf(v.z);
        base[(size_t)(c + 3) * 8] = f2bf(v.w);
    } else {
        int i0 = ((bid - 2048) * 256 + t) * 8;
        float4 a = *reinterpret_cast<const float4*>(x + i0);
        float4 b = *reinterpret_cast<const float4*>(x + i0 + 4);
        union { unsigned short s[8]; uint4 v; } u;
        u.s[0] = f2bf(a.x); u.s[1] = f2bf(a.y); u.s[2] = f2bf(a.z); u.s[3] = f2bf(a.w);
        u.s[4] = f2bf(b.x); u.s[5] = f2bf(b.y); u.s[6] = f2bf(b.z); u.s[7] = f2bf(b.w);
        *reinterpret_cast<uint4*>(xbf + i0) = u.v;
    }
}

// ---- fused: one block per b, 1024 threads (16 waves, 4/SIMD) ----
// G: wave w -> n-tile w (16 MFMA).  P: thread owns rows {lane+64r}, wave w
// handles j in [16w,16w+16).  Reduce over 16 waves in LDS.
__global__ __launch_bounds__(1024) void mbd_fused(const unsigned short* __restrict__ xbf,
                                                  const unsigned short* __restrict__ Tt,
                                                  const float* __restrict__ x,
                                                  float* __restrict__ out) {
    __shared__ float Msh[ND * MS];     // 20 KB
    __shared__ float red[16 * ND];     // 16 KB
    const int b = blockIdx.x;
    const int t = threadIdx.x;
    const int lane = t & 63;
    const int w = t >> 6;
    const int rc = lane & 15;  // A-row in tile == B col (i) == D col
    const int g = lane >> 4;   // k-group

    // ---- phase G ----
    const bf16x8* Av = reinterpret_cast<const bf16x8*>(xbf);
    const bf16x8* Bv = reinterpret_cast<const bf16x8*>(Tt);
    const int arow = w * 16 + rc;
    f32x4 acc = {0.f, 0.f, 0.f, 0.f};
#pragma unroll 4
    for (int k = 0; k < 16; ++k) {
        bf16x8 afr = Av[(size_t)arow * 64 + k * 4 + g];
        bf16x8 bfr = Bv[(size_t)(k * 4 + g) * CD + b * 16 + rc];
        acc = __builtin_amdgcn_mfma_f32_16x16x32_bf16(afr, bfr, acc, 0, 0, 0);
    }
    // D layout (m89, R6-verified): col = lane&15, row = g*4 + r
#pragma unroll
    for (int r = 0; r < 4; ++r)
        Msh[(w * 16 + g * 4 + r) * MS + rc] = acc[r];
    __syncthreads();

    // ---- phase P ----
    float mr[4][ID];
#pragma unroll
    for (int r = 0; r < 4; ++r)
#pragma unroll
        for (int ii = 0; ii < 4; ++ii) {
            float4 v = *reinterpret_cast<const float4*>(&Msh[(lane + 64 * r) * MS + ii * 4]);
            mr[r][ii * 4] = v.x; mr[r][ii * 4 + 1] = v.y;
            mr[r][ii * 4 + 2] = v.z; mr[r][ii * 4 + 3] = v.w;
        }

    float pacc[4] = {0.f, 0.f, 0.f, 0.f};
    const int j0 = w * 16;
#pragma unroll 2
    for (int j = j0; j < j0 + 16; ++j) {
        float mj[ID];
#pragma unroll
        for (int ii = 0; ii < 4; ++ii) {  // uniform addr -> broadcast b128
            float4 v = *reinterpret_cast<const float4*>(&Msh[j * MS + ii * 4]);
            mj[ii * 4] = v.x; mj[ii * 4 + 1] = v.y;
            mj[ii * 4 + 2] = v.z; mj[ii * 4 + 3] = v.w;
        }
#pragma unroll
        for (int r = 0; r < 4; ++r) {
            float s0 = 0.f, s1 = 0.f, s2 = 0.f, s3 = 0.f;
#pragma unroll
            for (int i = 0; i < ID; i += 4) {
                s0 += fabsf(mr[r][i + 0] - mj[i + 0]);
                s1 += fabsf(mr[r][i + 1] - mj[i + 1]);
                s2 += fabsf(mr[r][i + 2] - mj[i + 2]);
                s3 += fabsf(mr[r][i + 3] - mj[i + 3]);
            }
            pacc[r] += __expf(-((s0 + s1) + (s2 + s3)));
        }
    }
#pragma unroll
    for (int r = 0; r < 4; ++r) red[w * ND + lane + 64 * r] = pacc[r];
    __syncthreads();

    // ---- reduce + write ----
    if (t < ND) {
        float s = -1.0f;  // self-pair exp(0)=1 cancels
#pragma unroll
        for (int w2 = 0; w2 < 16; ++w2) s += red[w2 * ND + t];
        out[(size_t)t * OUT_F + IN_F + b] = s;
    } else if (t < ND + IN_F / 4) {
        const int q = t - ND;  // concat: out[b,0:512] = x[b,:]
        float4 v = reinterpret_cast<const float4*>(x + (size_t)b * IN_F)[q];
        reinterpret_cast<float4*>(out + (size_t)b * OUT_F)[q] = v;
    }
}

// ---- fallback (ws too small): R8 single kernel (known-good 46us) ----
__global__ __launch_bounds__(256) void mbd_one(const float* __restrict__ x,
                                               const float* __restrict__ T,
                                               float* __restrict__ out) {
    __shared__ float Tsh[IN_F * ID];
    __shared__ float Msh[ND * MS];
    const int b = blockIdx.x;
    const int t = threadIdx.x;
    const int lane = t & 63;
    const int w = t >> 6;
#pragma unroll
    for (int s = 0; s < 8; ++s) {
        int q = s * 256 + t;
        int f = q >> 2, c4 = (q & 3) << 2;
        float4 v = *reinterpret_cast<const float4*>(T + (size_t)f * CD + b * ID + c4);
        *reinterpret_cast<float4*>(&Tsh[f * ID + c4]) = v;
    }
    __syncthreads();
    const int rc = lane & 15;
    const int g = lane >> 4;
    f32x4 acc[4];
#pragma unroll
    for (int i = 0; i < 4; ++i) acc[i] = f32x4{0.f, 0.f, 0.f, 0.f};
    const float* xw = x + (size_t)(w * 64 + rc) * IN_F;
    for (int k = 0; k < 16; ++k) {
        bf16x8 bfr;
#pragma unroll
        for (int e = 0; e < 8; ++e) bfr[e] = (__bf16)Tsh[(k * 32 + g * 8 + e) * ID + rc];
        const int xo = k * 32 + g * 8;
#pragma unroll
        for (int nt = 0; nt < 4; ++nt) {
            const float* ap = xw + (size_t)nt * 16 * IN_F + xo;
            float4 a0 = *reinterpret_cast<const float4*>(ap);
            float4 a1 = *reinterpret_cast<const float4*>(ap + 4);
            bf16x8 afr;
            afr[0] = (__bf16)a0.x; afr[1] = (__bf16)a0.y;
            afr[2] = (__bf16)a0.z; afr[3] = (__bf16)a0.w;
            afr[4] = (__bf16)a1.x; afr[5] = (__bf16)a1.y;
            afr[6] = (__bf16)a1.z; afr[7] = (__bf16)a1.w;
            acc[nt] = __builtin_amdgcn_mfma_f32_16x16x32_bf16(afr, bfr, acc[nt], 0, 0, 0);
        }
    }
#pragma unroll
    for (int nt = 0; nt < 4; ++nt)
#pragma unroll
        for (int r = 0; r < 4; ++r)
            Msh[((w * 4 + nt) * 16 + g * 4 + r) * MS + rc] = acc[nt][r];
    __syncthreads();
    float mr[4][ID];
#pragma unroll
    for (int r = 0; r < 4; ++r)
#pragma unroll
        for (int ii = 0; ii < 4; ++ii) {
            float4 v = *reinterpret_cast<const float4*>(&Msh[(lane + 64 * r) * MS + ii * 4]);
            mr[r][ii * 4] = v.x; mr[r][ii * 4 + 1] = v.y;
            mr[r][ii * 4 + 2] = v.z; mr[r][ii * 4 + 3] = v.w;
        }
    float pacc[4] = {0.f, 0.f, 0.f, 0.f};
    const int j0 = w * 64;
#pragma unroll 2
    for (int j = j0; j < j0 + 64; ++j) {
        float mj[ID];
#pragma unroll
        for (int ii = 0; ii < 4; ++ii) {
            float4 v = *reinterpret_cast<const float4*>(&Msh[j * MS + ii * 4]);
            mj[ii * 4] = v.x; mj[ii * 4 + 1] = v.y;
            mj[ii * 4 + 2] = v.z; mj[ii * 4 + 3] = v.w;
        }
#pragma unroll
        for (int r = 0; r < 4; ++r) {
            float s0 = 0.f, s1 = 0.f, s2 = 0.f, s3 = 0.f;
#pragma unroll
            for (int i = 0; i < ID; i += 4) {
                s0 += fabsf(mr[r][i + 0] - mj[i + 0]);
                s1 += fabsf(mr[r][i + 1] - mj[i + 1]);
                s2 += fabsf(mr[r][i + 2] - mj[i + 2]);
                s3 += fabsf(mr[r][i + 3] - mj[i + 3]);
            }
            pacc[r] += __expf(-((s0 + s1) + (s2 + s3)));
        }
    }
    float* red = Tsh;
#pragma unroll
    for (int r = 0; r < 4; ++r) red[w * 256 + lane + 64 * r] = pacc[r];
    __syncthreads();
    {
        float s = red[t] + red[256 + t] + red[512 + t] + red[768 + t] - 1.0f;
        out[(size_t)t * OUT_F + IN_F + b] = s;
    }
    if (t < IN_F / 4) {
        float4 v = reinterpret_cast<const float4*>(x + (size_t)b * IN_F)[t];
        reinterpret_cast<float4*>(out + (size_t)b * OUT_F)[t] = v;
    }
}

extern "C" void kernel_launch(void* const* d_in, const int* in_sizes, int n_in,
                              void* d_out, int out_size, void* d_ws, size_t ws_size,
                              hipStream_t stream) {
    const float* x = (const float*)d_in[0];
    const float* T = (const float*)d_in[1];
    float* out = (float*)d_out;

    const size_t off_xbf = 4194304;           // Tt: 4 MB
    const size_t needed = off_xbf + 262144;   // + xbf 256 KB

    if (ws_size >= needed) {
        unsigned short* Tt = (unsigned short*)d_ws;
        unsigned short* xbf = (unsigned short*)((char*)d_ws + off_xbf);
        prep_kernel<<<dim3(2112), dim3(256), 0, stream>>>(x, T, Tt, xbf);
        mbd_fused<<<dim3(BD), dim3(1024), 0, stream>>>(xbf, Tt, x, out);
    } else {
        mbd_one<<<dim3(BD), dim3(256), 0, stream>>>(x, T, out);
    }
}

// Round 10
// 41.158 us; speedup vs baseline: 1.1712x; 1.1712x over previous
//
#include <hip/hip_runtime.h>
#include <stdint.h>

#define IN_F 512
#define OUT_F 768
#define BD 256
#define ID 16
#define ND 256
#define CD 4096   // B*I columns
#define MS 20     // Msh row stride (16+4 pad)
#define TLP 1028  // prep LDS row stride (1024 + 4 pad)

typedef __bf16 bf16x8 __attribute__((ext_vector_type(8)));
typedef float f32x4 __attribute__((ext_vector_type(4)));

__device__ __forceinline__ unsigned short f2bf(float f) {
    union { float f; uint32_t u; } v; v.f = f;
    uint32_t u = v.u + 0x7FFFu + ((v.u >> 16) & 1u);  // RNE
    return (unsigned short)(u >> 16);
}

// ---- prep v2: coalesced-both-sides transpose T -> Tt [f>>3][c][f&7] bf16 ----
// blocks [0,256): T-tile (f-octet oct, col-group cg of 1024). [256,320): x.
__global__ __launch_bounds__(256) void prep_kernel(const float* __restrict__ x,
                                                   const float* __restrict__ T,
                                                   unsigned short* __restrict__ Tt,
                                                   unsigned short* __restrict__ xbf) {
    __shared__ float Tl[8 * TLP];  // ~32.9 KB
    const int bid = blockIdx.x;
    const int t = threadIdx.x;
    if (bid < 256) {
        const int oct = bid >> 2;   // 0..63  (f0 = oct*8)
        const int cg = bid & 3;     // 0..3   (cols cg*1024..+1024)
        const int f0 = oct * 8;
        // coalesced read: 8 rows x 1024 cols f32
#pragma unroll
        for (int s = 0; s < 8; ++s) {
            float4 v = *reinterpret_cast<const float4*>(
                T + (size_t)(f0 + s) * CD + cg * 1024 + t * 4);
            *reinterpret_cast<float4*>(&Tl[s * TLP + t * 4]) = v;
        }
        __syncthreads();
        // coalesced write: thread t emits units c = cg*1024 + t*4 + {0..3}
#pragma unroll
        for (int u = 0; u < 4; ++u) {
            const int c = t * 4 + u;
            union { unsigned short s[8]; uint4 v; } p;
#pragma unroll
            for (int e = 0; e < 8; ++e) p.s[e] = f2bf(Tl[e * TLP + c]);
            *reinterpret_cast<uint4*>(Tt + ((size_t)oct * CD + cg * 1024 + c) * 8) = p.v;
        }
    } else {
        int i0 = ((bid - 256) * 256 + t) * 8;
        float4 a = *reinterpret_cast<const float4*>(x + i0);
        float4 b = *reinterpret_cast<const float4*>(x + i0 + 4);
        union { unsigned short s[8]; uint4 v; } u;
        u.s[0] = f2bf(a.x); u.s[1] = f2bf(a.y); u.s[2] = f2bf(a.z); u.s[3] = f2bf(a.w);
        u.s[4] = f2bf(b.x); u.s[5] = f2bf(b.y); u.s[6] = f2bf(b.z); u.s[7] = f2bf(b.w);
        *reinterpret_cast<uint4*>(xbf + i0) = u.v;
    }
}

// ---- fused: one block per b, 1024 threads (16 waves, 4/SIMD) — R9-proven ----
__global__ __launch_bounds__(1024) void mbd_fused(const unsigned short* __restrict__ xbf,
                                                  const unsigned short* __restrict__ Tt,
                                                  const float* __restrict__ x,
                                                  float* __restrict__ out) {
    __shared__ float Msh[ND * MS];     // 20 KB
    __shared__ float red[16 * ND];     // 16 KB
    const int b = blockIdx.x;
    const int t = threadIdx.x;
    const int lane = t & 63;
    const int w = t >> 6;
    const int rc = lane & 15;  // A-row in tile == B col (i) == D col
    const int g = lane >> 4;   // k-group

    // ---- phase G ----
    const bf16x8* Av = reinterpret_cast<const bf16x8*>(xbf);
    const bf16x8* Bv = reinterpret_cast<const bf16x8*>(Tt);
    const int arow = w * 16 + rc;
    f32x4 acc = {0.f, 0.f, 0.f, 0.f};
#pragma unroll 4
    for (int k = 0; k < 16; ++k) {
        bf16x8 afr = Av[(size_t)arow * 64 + k * 4 + g];
        bf16x8 bfr = Bv[(size_t)(k * 4 + g) * CD + b * 16 + rc];
        acc = __builtin_amdgcn_mfma_f32_16x16x32_bf16(afr, bfr, acc, 0, 0, 0);
    }
    // D layout (m89, R6-verified): col = lane&15, row = g*4 + r
#pragma unroll
    for (int r = 0; r < 4; ++r)
        Msh[(w * 16 + g * 4 + r) * MS + rc] = acc[r];
    __syncthreads();

    // ---- phase P ----
    float mr[4][ID];
#pragma unroll
    for (int r = 0; r < 4; ++r)
#pragma unroll
        for (int ii = 0; ii < 4; ++ii) {
            float4 v = *reinterpret_cast<const float4*>(&Msh[(lane + 64 * r) * MS + ii * 4]);
            mr[r][ii * 4] = v.x; mr[r][ii * 4 + 1] = v.y;
            mr[r][ii * 4 + 2] = v.z; mr[r][ii * 4 + 3] = v.w;
        }

    float pacc[4] = {0.f, 0.f, 0.f, 0.f};
    const int j0 = w * 16;
#pragma unroll 2
    for (int j = j0; j < j0 + 16; ++j) {
        float mj[ID];
#pragma unroll
        for (int ii = 0; ii < 4; ++ii) {  // uniform addr -> broadcast b128
            float4 v = *reinterpret_cast<const float4*>(&Msh[j * MS + ii * 4]);
            mj[ii * 4] = v.x; mj[ii * 4 + 1] = v.y;
            mj[ii * 4 + 2] = v.z; mj[ii * 4 + 3] = v.w;
        }
#pragma unroll
        for (int r = 0; r < 4; ++r) {
            float s0 = 0.f, s1 = 0.f, s2 = 0.f, s3 = 0.f;
#pragma unroll
            for (int i = 0; i < ID; i += 4) {
                s0 += fabsf(mr[r][i + 0] - mj[i + 0]);
                s1 += fabsf(mr[r][i + 1] - mj[i + 1]);
                s2 += fabsf(mr[r][i + 2] - mj[i + 2]);
                s3 += fabsf(mr[r][i + 3] - mj[i + 3]);
            }
            pacc[r] += __expf(-((s0 + s1) + (s2 + s3)));
        }
    }
#pragma unroll
    for (int r = 0; r < 4; ++r) red[w * ND + lane + 64 * r] = pacc[r];
    __syncthreads();

    // ---- reduce + write ----
    if (t < ND) {
        float s = -1.0f;  // self-pair exp(0)=1 cancels
#pragma unroll
        for (int w2 = 0; w2 < 16; ++w2) s += red[w2 * ND + t];
        out[(size_t)t * OUT_F + IN_F + b] = s;
    } else if (t < ND + IN_F / 4) {
        const int q = t - ND;  // concat: out[b,0:512] = x[b,:]
        float4 v = reinterpret_cast<const float4*>(x + (size_t)b * IN_F)[q];
        reinterpret_cast<float4*>(out + (size_t)b * OUT_F)[q] = v;
    }
}

// ---- fallback (ws too small): R8 single kernel (known-good 46us) ----
__global__ __launch_bounds__(256) void mbd_one(const float* __restrict__ x,
                                               const float* __restrict__ T,
                                               float* __restrict__ out) {
    __shared__ float Tsh[IN_F * ID];
    __shared__ float Msh[ND * MS];
    const int b = blockIdx.x;
    const int t = threadIdx.x;
    const int lane = t & 63;
    const int w = t >> 6;
#pragma unroll
    for (int s = 0; s < 8; ++s) {
        int q = s * 256 + t;
        int f = q >> 2, c4 = (q & 3) << 2;
        float4 v = *reinterpret_cast<const float4*>(T + (size_t)f * CD + b * ID + c4);
        *reinterpret_cast<float4*>(&Tsh[f * ID + c4]) = v;
    }
    __syncthreads();
    const int rc = lane & 15;
    const int g = lane >> 4;
    f32x4 acc[4];
#pragma unroll
    for (int i = 0; i < 4; ++i) acc[i] = f32x4{0.f, 0.f, 0.f, 0.f};
    const float* xw = x + (size_t)(w * 64 + rc) * IN_F;
    for (int k = 0; k < 16; ++k) {
        bf16x8 bfr;
#pragma unroll
        for (int e = 0; e < 8; ++e) bfr[e] = (__bf16)Tsh[(k * 32 + g * 8 + e) * ID + rc];
        const int xo = k * 32 + g * 8;
#pragma unroll
        for (int nt = 0; nt < 4; ++nt) {
            const float* ap = xw + (size_t)nt * 16 * IN_F + xo;
            float4 a0 = *reinterpret_cast<const float4*>(ap);
            float4 a1 = *reinterpret_cast<const float4*>(ap + 4);
            bf16x8 afr;
            afr[0] = (__bf16)a0.x; afr[1] = (__bf16)a0.y;
            afr[2] = (__bf16)a0.z; afr[3] = (__bf16)a0.w;
            afr[4] = (__bf16)a1.x; afr[5] = (__bf16)a1.y;
            afr[6] = (__bf16)a1.z; afr[7] = (__bf16)a1.w;
            acc[nt] = __builtin_amdgcn_mfma_f32_16x16x32_bf16(afr, bfr, acc[nt], 0, 0, 0);
        }
    }
#pragma unroll
    for (int nt = 0; nt < 4; ++nt)
#pragma unroll
        for (int r = 0; r < 4; ++r)
            Msh[((w * 4 + nt) * 16 + g * 4 + r) * MS + rc] = acc[nt][r];
    __syncthreads();
    float mr[4][ID];
#pragma unroll
    for (int r = 0; r < 4; ++r)
#pragma unroll
        for (int ii = 0; ii < 4; ++ii) {
            float4 v = *reinterpret_cast<const float4*>(&Msh[(lane + 64 * r) * MS + ii * 4]);
            mr[r][ii * 4] = v.x; mr[r][ii * 4 + 1] = v.y;
            mr[r][ii * 4 + 2] = v.z; mr[r][ii * 4 + 3] = v.w;
        }
    float pacc[4] = {0.f, 0.f, 0.f, 0.f};
    const int j0 = w * 64;
#pragma unroll 2
    for (int j = j0; j < j0 + 64; ++j) {
        float mj[ID];
#pragma unroll
        for (int ii = 0; ii < 4; ++ii) {
            float4 v = *reinterpret_cast<const float4*>(&Msh[j * MS + ii * 4]);
            mj[ii * 4] = v.x; mj[ii * 4 + 1] = v.y;
            mj[ii * 4 + 2] = v.z; mj[ii * 4 + 3] = v.w;
        }
#pragma unroll
        for (int r = 0; r < 4; ++r) {
            float s0 = 0.f, s1 = 0.f, s2 = 0.f, s3 = 0.f;
#pragma unroll
            for (int i = 0; i < ID; i += 4) {
                s0 += fabsf(mr[r][i + 0] - mj[i + 0]);
                s1 += fabsf(mr[r][i + 1] - mj[i + 1]);
                s2 += fabsf(mr[r][i + 2] - mj[i + 2]);
                s3 += fabsf(mr[r][i + 3] - mj[i + 3]);
            }
            pacc[r] += __expf(-((s0 + s1) + (s2 + s3)));
        }
    }
    float* red = Tsh;
#pragma unroll
    for (int r = 0; r < 4; ++r) red[w * 256 + lane + 64 * r] = pacc[r];
    __syncthreads();
    {
        float s = red[t] + red[256 + t] + red[512 + t] + red[768 + t] - 1.0f;
        out[(size_t)t * OUT_F + IN_F + b] = s;
    }
    if (t < IN_F / 4) {
        float4 v = reinterpret_cast<const float4*>(x + (size_t)b * IN_F)[t];
        reinterpret_cast<float4*>(out + (size_t)b * OUT_F)[t] = v;
    }
}

extern "C" void kernel_launch(void* const* d_in, const int* in_sizes, int n_in,
                              void* d_out, int out_size, void* d_ws, size_t ws_size,
                              hipStream_t stream) {
    const float* x = (const float*)d_in[0];
    const float* T = (const float*)d_in[1];
    float* out = (float*)d_out;

    const size_t off_xbf = 4194304;           // Tt: 4 MB
    const size_t needed = off_xbf + 262144;   // + xbf 256 KB

    if (ws_size >= needed) {
        unsigned short* Tt = (unsigned short*)d_ws;
        unsigned short* xbf = (unsigned short*)((char*)d_ws + off_xbf);
        prep_kernel<<<dim3(320), dim3(256), 0, stream>>>(x, T, Tt, xbf);
        mbd_fused<<<dim3(BD), dim3(1024), 0, stream>>>(xbf, Tt, x, out);
    } else {
        mbd_one<<<dim3(BD), dim3(256), 0, stream>>>(x, T, out);
    }
}

// Round 11
// 39.124 us; speedup vs baseline: 1.2320x; 1.0520x over previous
//
#include <hip/hip_runtime.h>
#include <stdint.h>

#define IN_F 512
#define OUT_F 768
#define BD 256
#define ID 16
#define ND 256
#define CD 4096   // B*I columns in T
#define MS 20     // Msh row stride (16+4 pad)

typedef __bf16 bf16x8 __attribute__((ext_vector_type(8)));
typedef float f32x4 __attribute__((ext_vector_type(4)));

__device__ __forceinline__ unsigned short f2bf(float f) {
    union { float f; uint32_t u; } v; v.f = f;
    uint32_t u = v.u + 0x7FFFu + ((v.u >> 16) & 1u);  // RNE
    return (unsigned short)(u >> 16);
}

// ---- xprep: [0,128): x -> xbf bf16 row-major; [128,256): concat copy ----
__global__ __launch_bounds__(256) void xprep_kernel(const float* __restrict__ x,
                                                    unsigned short* __restrict__ xbf,
                                                    float* __restrict__ out) {
    const int bid = blockIdx.x;
    const int t = threadIdx.x;
    if (bid < 128) {
        int i0 = (bid * 256 + t) * 8;
        float4 a = *reinterpret_cast<const float4*>(x + i0);
        float4 c = *reinterpret_cast<const float4*>(x + i0 + 4);
        union { unsigned short s[8]; uint4 v; } u;
        u.s[0] = f2bf(a.x); u.s[1] = f2bf(a.y); u.s[2] = f2bf(a.z); u.s[3] = f2bf(a.w);
        u.s[4] = f2bf(c.x); u.s[5] = f2bf(c.y); u.s[6] = f2bf(c.z); u.s[7] = f2bf(c.w);
        *reinterpret_cast<uint4*>(xbf + i0) = u.v;
    } else {
        // concat: out[r, 0:512] = x[r, :]  (2 rows per block, 128 f4/row)
        int r = (bid - 128) * 2 + (t >> 7);
        int q = t & 127;
        float4 v = reinterpret_cast<const float4*>(x + (size_t)r * IN_F)[q];
        reinterpret_cast<float4*>(out + (size_t)r * OUT_F)[q] = v;
    }
}

// ---- fused2: one block per b, 1024 threads (16 waves). T-transpose inlined:
// stage T[:,b,:] f32 coalesced -> LDS; convert once to fragment layout
// Tfrag[kg][rc][e] so phase-G B-reads are contiguous conflict-free b128.
__global__ __launch_bounds__(1024) void mbd_fused2(const unsigned short* __restrict__ xbf,
                                                   const float* __restrict__ T,
                                                   float* __restrict__ out) {
    __shared__ __align__(16) unsigned char smem[32768 + 16384 + 20480];  // 68 KB
    float* Tst = (float*)smem;                                 // 32 KB (reused as red)
    unsigned short* Tfrag = (unsigned short*)(smem + 32768);   // 16 KB
    float* Msh = (float*)(smem + 32768 + 16384);               // 20 KB
    float* red = (float*)smem;                                 // alias of Tst

    const int b = blockIdx.x;
    const int t = threadIdx.x;
    const int lane = t & 63;
    const int w = t >> 6;
    const int rc = lane & 15;  // A-row in tile == B col (i) == D col
    const int g = lane >> 4;   // k-group

    // ---- stage T[:, b*16..+16) (512 x 16 f32 = 32 KB), coalesced ----
#pragma unroll
    for (int s = 0; s < 2; ++s) {
        int q = s * 1024 + t;
        int f = q >> 2, c4 = (q & 3) << 2;
        float4 v = *reinterpret_cast<const float4*>(T + (size_t)f * CD + b * ID + c4);
        *reinterpret_cast<float4*>(&Tst[f * ID + c4]) = v;
    }
    __syncthreads();

    // ---- convert: Tfrag[kg*128 + c*8 + e] = bf16(T[kg*8+e][b*16+c]) ----
    {
        const int kg = t >> 4;  // 0..63
        const int c = t & 15;
        union { unsigned short s[8]; uint4 v; } p;
#pragma unroll
        for (int e = 0; e < 8; ++e) p.s[e] = f2bf(Tst[(kg * 8 + e) * ID + c]);
        *reinterpret_cast<uint4*>(Tfrag + (size_t)t * 8) = p.v;  // coalesced b128
    }
    __syncthreads();

    // ---- phase G: wave w -> n-tile w; B-frag = 1 contiguous b128 per k ----
    const bf16x8* Av = reinterpret_cast<const bf16x8*>(xbf);
    const bf16x8* Bf = reinterpret_cast<const bf16x8*>(Tfrag);
    const int arow = w * 16 + rc;
    f32x4 acc = {0.f, 0.f, 0.f, 0.f};
#pragma unroll 4
    for (int k = 0; k < 16; ++k) {
        bf16x8 afr = Av[(size_t)arow * 64 + k * 4 + g];
        bf16x8 bfr = Bf[(k * 4 + g) * 16 + rc];  // kg*256B + rc*16B: conflict-free
        acc = __builtin_amdgcn_mfma_f32_16x16x32_bf16(afr, bfr, acc, 0, 0, 0);
    }
    // D layout (m89, R6/R9-verified): col = lane&15, row = g*4 + r
#pragma unroll
    for (int r = 0; r < 4; ++r)
        Msh[(w * 16 + g * 4 + r) * MS + rc] = acc[r];
    __syncthreads();

    // ---- phase P: thread owns rows {lane+64r}; wave w handles 16 j ----
    float mr[4][ID];
#pragma unroll
    for (int r = 0; r < 4; ++r)
#pragma unroll
        for (int ii = 0; ii < 4; ++ii) {
            float4 v = *reinterpret_cast<const float4*>(&Msh[(lane + 64 * r) * MS + ii * 4]);
            mr[r][ii * 4] = v.x; mr[r][ii * 4 + 1] = v.y;
            mr[r][ii * 4 + 2] = v.z; mr[r][ii * 4 + 3] = v.w;
        }

    float pacc[4] = {0.f, 0.f, 0.f, 0.f};
    const int j0 = w * 16;
#pragma unroll 2
    for (int j = j0; j < j0 + 16; ++j) {
        float mj[ID];
#pragma unroll
        for (int ii = 0; ii < 4; ++ii) {  // uniform addr -> broadcast b128
            float4 v = *reinterpret_cast<const float4*>(&Msh[j * MS + ii * 4]);
            mj[ii * 4] = v.x; mj[ii * 4 + 1] = v.y;
            mj[ii * 4 + 2] = v.z; mj[ii * 4 + 3] = v.w;
        }
#pragma unroll
        for (int r = 0; r < 4; ++r) {
            float s0 = 0.f, s1 = 0.f, s2 = 0.f, s3 = 0.f;
#pragma unroll
            for (int i = 0; i < ID; i += 4) {
                s0 += fabsf(mr[r][i + 0] - mj[i + 0]);
                s1 += fabsf(mr[r][i + 1] - mj[i + 1]);
                s2 += fabsf(mr[r][i + 2] - mj[i + 2]);
                s3 += fabsf(mr[r][i + 3] - mj[i + 3]);
            }
            pacc[r] += __expf(-((s0 + s1) + (s2 + s3)));
        }
    }
#pragma unroll
    for (int r = 0; r < 4; ++r) red[w * ND + lane + 64 * r] = pacc[r];
    __syncthreads();

    // ---- reduce + write (concat handled by xprep) ----
    if (t < ND) {
        float s = -1.0f;  // self-pair exp(0)=1 cancels
#pragma unroll
        for (int w2 = 0; w2 < 16; ++w2) s += red[w2 * ND + t];
        out[(size_t)t * OUT_F + IN_F + b] = s;
    }
}

// ---- fallback (ws too small): R8 single kernel (known-good ~46us) ----
__global__ __launch_bounds__(256) void mbd_one(const float* __restrict__ x,
                                               const float* __restrict__ T,
                                               float* __restrict__ out) {
    __shared__ float Tsh[IN_F * ID];
    __shared__ float Msh[ND * MS];
    const int b = blockIdx.x;
    const int t = threadIdx.x;
    const int lane = t & 63;
    const int w = t >> 6;
#pragma unroll
    for (int s = 0; s < 8; ++s) {
        int q = s * 256 + t;
        int f = q >> 2, c4 = (q & 3) << 2;
        float4 v = *reinterpret_cast<const float4*>(T + (size_t)f * CD + b * ID + c4);
        *reinterpret_cast<float4*>(&Tsh[f * ID + c4]) = v;
    }
    __syncthreads();
    const int rc = lane & 15;
    const int g = lane >> 4;
    f32x4 acc[4];
#pragma unroll
    for (int i = 0; i < 4; ++i) acc[i] = f32x4{0.f, 0.f, 0.f, 0.f};
    const float* xw = x + (size_t)(w * 64 + rc) * IN_F;
    for (int k = 0; k < 16; ++k) {
        bf16x8 bfr;
#pragma unroll
        for (int e = 0; e < 8; ++e) bfr[e] = (__bf16)Tsh[(k * 32 + g * 8 + e) * ID + rc];
        const int xo = k * 32 + g * 8;
#pragma unroll
        for (int nt = 0; nt < 4; ++nt) {
            const float* ap = xw + (size_t)nt * 16 * IN_F + xo;
            float4 a0 = *reinterpret_cast<const float4*>(ap);
            float4 a1 = *reinterpret_cast<const float4*>(ap + 4);
            bf16x8 afr;
            afr[0] = (__bf16)a0.x; afr[1] = (__bf16)a0.y;
            afr[2] = (__bf16)a0.z; afr[3] = (__bf16)a0.w;
            afr[4] = (__bf16)a1.x; afr[5] = (__bf16)a1.y;
            afr[6] = (__bf16)a1.z; afr[7] = (__bf16)a1.w;
            acc[nt] = __builtin_amdgcn_mfma_f32_16x16x32_bf16(afr, bfr, acc[nt], 0, 0, 0);
        }
    }
#pragma unroll
    for (int nt = 0; nt < 4; ++nt)
#pragma unroll
        for (int r = 0; r < 4; ++r)
            Msh[((w * 4 + nt) * 16 + g * 4 + r) * MS + rc] = acc[nt][r];
    __syncthreads();
    float mr[4][ID];
#pragma unroll
    for (int r = 0; r < 4; ++r)
#pragma unroll
        for (int ii = 0; ii < 4; ++ii) {
            float4 v = *reinterpret_cast<const float4*>(&Msh[(lane + 64 * r) * MS + ii * 4]);
            mr[r][ii * 4] = v.x; mr[r][ii * 4 + 1] = v.y;
            mr[r][ii * 4 + 2] = v.z; mr[r][ii * 4 + 3] = v.w;
        }
    float pacc[4] = {0.f, 0.f, 0.f, 0.f};
    const int j0 = w * 64;
#pragma unroll 2
    for (int j = j0; j < j0 + 64; ++j) {
        float mj[ID];
#pragma unroll
        for (int ii = 0; ii < 4; ++ii) {
            float4 v = *reinterpret_cast<const float4*>(&Msh[j * MS + ii * 4]);
            mj[ii * 4] = v.x; mj[ii * 4 + 1] = v.y;
            mj[ii * 4 + 2] = v.z; mj[ii * 4 + 3] = v.w;
        }
#pragma unroll
        for (int r = 0; r < 4; ++r) {
            float s0 = 0.f, s1 = 0.f, s2 = 0.f, s3 = 0.f;
#pragma unroll
            for (int i = 0; i < ID; i += 4) {
                s0 += fabsf(mr[r][i + 0] - mj[i + 0]);
                s1 += fabsf(mr[r][i + 1] - mj[i + 1]);
                s2 += fabsf(mr[r][i + 2] - mj[i + 2]);
                s3 += fabsf(mr[r][i + 3] - mj[i + 3]);
            }
            pacc[r] += __expf(-((s0 + s1) + (s2 + s3)));
        }
    }
    float* red = Tsh;
#pragma unroll
    for (int r = 0; r < 4; ++r) red[w * 256 + lane + 64 * r] = pacc[r];
    __syncthreads();
    {
        float s = red[t] + red[256 + t] + red[512 + t] + red[768 + t] - 1.0f;
        out[(size_t)t * OUT_F + IN_F + b] = s;
    }
    if (t < IN_F / 4) {
        float4 v = reinterpret_cast<const float4*>(x + (size_t)b * IN_F)[t];
        reinterpret_cast<float4*>(out + (size_t)b * OUT_F)[t] = v;
    }
}

extern "C" void kernel_launch(void* const* d_in, const int* in_sizes, int n_in,
                              void* d_out, int out_size, void* d_ws, size_t ws_size,
                              hipStream_t stream) {
    const float* x = (const float*)d_in[0];
    const float* T = (const float*)d_in[1];
    float* out = (float*)d_out;

    const size_t needed = (size_t)ND * IN_F * 2;  // xbf: 256 KB

    if (ws_size >= needed) {
        unsigned short* xbf = (unsigned short*)d_ws;
        xprep_kernel<<<dim3(256), dim3(256), 0, stream>>>(x, xbf, out);
        mbd_fused2<<<dim3(BD), dim3(1024), 0, stream>>>(xbf, T, out);
    } else {
        mbd_one<<<dim3(BD), dim3(256), 0, stream>>>(x, T, out);
    }
}